// Round 5
// baseline (169.951 us; speedup 1.0000x reference)
//
#include <hip/hip_runtime.h>

// MHA: B=8, N=1024, D=768, H=12, HD=64. FLOAT32 in/out, bf16 MFMA internally.
// Round 20: out_proj occupancy experiment (single variable).
//   attn: round-15/18 form verbatim (4 measurements at 42-45us; r16/r17/r19
//     experiments all <=0; occupancy hard-capped at 12 waves/CU by M=32).
//   out_proj: 64x96 tiles, grid (128,8) = 1024 blocks = 4 blocks/CU
//     = 16 waves/CU (was 128x96, 512 blocks, 2/CU = 8 waves/CU).
//     Theory: out_proj is latency-bound (12 global prefetch loads/k-iter
//     covered by only 8 waves/CU). LDS 23KB/block, acc 3x2 frags ~80 VGPR.
//   qkv/prep unchanged.

typedef __attribute__((ext_vector_type(8))) short short8;   // 8 x bf16 bits
typedef __attribute__((ext_vector_type(4))) float floatx4;  // MFMA acc

#define MFMA16(a, b, c) __builtin_amdgcn_mfma_f32_16x16x32_bf16((a), (b), (c), 0, 0, 0)

#if __has_builtin(__builtin_amdgcn_exp2f)
#define EXP2(x) __builtin_amdgcn_exp2f(x)
#else
#define EXP2(x) __expf(0.6931471805599453f * (x))
#endif
#if __has_builtin(__builtin_amdgcn_rcpf)
#define RCP(x) __builtin_amdgcn_rcpf(x)
#else
#define RCP(x) (1.0f / (x))
#endif

__device__ __forceinline__ unsigned short f2bf(float f) {
    union { float f; unsigned int i; } c;
    c.f = f;
    unsigned int i = c.i;
    return (unsigned short)((i + 0x7fffu + ((i >> 16) & 1u)) >> 16);  // RNE
}
__device__ __forceinline__ unsigned short f2bf_trunc(float f) {
    union { float f; unsigned int i; } c;
    c.f = f;
    return (unsigned short)(c.i >> 16);
}

// ---------------------------------------------------------------------------
// Phase 0: Wt[h][e][k] = W[h][k][e] (bf16), Wo_bf = bf16(Wo).
// ---------------------------------------------------------------------------
__global__ __launch_bounds__(256) void prep_weights(
    const float* __restrict__ Wq, const float* __restrict__ Wk,
    const float* __restrict__ Wv, const float* __restrict__ Wo,
    unsigned short* __restrict__ Wqt, unsigned short* __restrict__ Wkt,
    unsigned short* __restrict__ Wvt, unsigned short* __restrict__ Wob)
{
    int tid = blockIdx.x * 256 + threadIdx.x;  // 0..147455
    if (tid < 49152) {                          // 12 heads * 4096 only
        int h = tid >> 12, r = tid & 4095;
        int e = r >> 6, k = r & 63;
        int src = h * 4096 + k * 64 + e, dst = h * 4096 + e * 64 + k;
        Wqt[dst] = f2bf(Wq[src]);
        Wkt[dst] = f2bf(Wk[src]);
        Wvt[dst] = f2bf(Wv[src]);
    }
    for (int i = tid; i < 589824; i += 147456) Wob[i] = f2bf(Wo[i]);
}

// ---------------------------------------------------------------------------
// Phase 1: staged + transposed QKV. grid (16, 96), block 256.
// ---------------------------------------------------------------------------
__global__ __launch_bounds__(256) void qkv_proj(
    const float* __restrict__ x,
    const unsigned short* __restrict__ Wqt, const unsigned short* __restrict__ Wkt,
    const unsigned short* __restrict__ Wvt,
    const float* __restrict__ bq, const float* __restrict__ bk,
    const float* __restrict__ bv,
    unsigned short* __restrict__ Q, unsigned short* __restrict__ K,
    unsigned short* __restrict__ Vt)
{
    __shared__ __align__(16) unsigned short xlds[64 * 72];  // 9216 B
    __shared__ __align__(16) unsigned short vlds[64 * 72];  // 9216 B

    const int bh = blockIdx.y;
    const int b = bh / 12, h = bh % 12;
    const int wave = threadIdx.x >> 6, lane = threadIdx.x & 63;
    const int lrow = lane & 15, quad = lane >> 4;
    const int row0 = blockIdx.x * 64;
    const float scale = 0.052058776672f;  // 768^-0.5 * log2(e): p = 2^s

    // ---- stage x tile, coalesced: 16 lanes per row, one float4 each ----
    {
        const int tr = threadIdx.x >> 4;        // 16 rows per round
        const int tc = (threadIdx.x & 15) * 4;  // 4 f32 per thread
        #pragma unroll
        for (int rr = 0; rr < 4; ++rr) {
            const int r = tr + rr * 16;
            const float* src = x + ((size_t)(b * 1024 + row0 + r)) * 768
                               + h * 64 + tc;
            float4 f = *(const float4*)src;
            unsigned short pkd[4];
            pkd[0] = f2bf(f.x); pkd[1] = f2bf(f.y);
            pkd[2] = f2bf(f.z); pkd[3] = f2bf(f.w);
            *(uint2*)&xlds[r * 72 + tc] = *(uint2*)pkd;  // 8B LDS write
        }
    }
    __syncthreads();

    short8 xb0 = *(const short8*)&xlds[(wave * 16 + lrow) * 72 + quad * 8];
    short8 xb1 = *(const short8*)&xlds[(wave * 16 + lrow) * 72 + 32 + quad * 8];

    const floatx4 zero = { 0.f, 0.f, 0.f, 0.f };

    const unsigned short* Wm[2] = { Wqt + h * 4096, Wkt + h * 4096 };
    const float* bm[2] = { bq + h * 64, bk + h * 64 };
    unsigned short* Om[2] = {
        Q + ((size_t)bh * 1024 + row0 + wave * 16 + lrow) * 64,
        K + ((size_t)bh * 1024 + row0 + wave * 16 + lrow) * 64 };
    #pragma unroll
    for (int m = 0; m < 2; ++m) {
        const unsigned short* W = Wm[m];
        #pragma unroll
        for (int t = 0; t < 4; ++t) {
            short8 wa0 = *(const short8*)(W + (t * 16 + lrow) * 64 + quad * 8);
            short8 wa1 = *(const short8*)(W + (t * 16 + lrow) * 64 + 32 + quad * 8);
            floatx4 acc = zero;
            acc = MFMA16(wa0, xb0, acc);
            acc = MFMA16(wa1, xb1, acc);
            float4 bias = *(const float4*)(bm[m] + t * 16 + quad * 4);
            const float bs[4] = { bias.x, bias.y, bias.z, bias.w };
            unsigned short pkd[4];
            #pragma unroll
            for (int r = 0; r < 4; ++r) {
                float v = acc[r] + bs[r];
                if (m == 0) v *= scale;
                pkd[r] = f2bf(v);
            }
            *(uint2*)(Om[m] + t * 16 + quad * 4) = *(uint2*)pkd;  // 8B store
        }
    }

    {
        const unsigned short* W = Wvt + h * 4096;
        const float* bvh = bv + h * 64;
        #pragma unroll
        for (int t = 0; t < 4; ++t) {
            short8 wa0 = *(const short8*)(W + (t * 16 + lrow) * 64 + quad * 8);
            short8 wa1 = *(const short8*)(W + (t * 16 + lrow) * 64 + 32 + quad * 8);
            floatx4 acc = zero;
            acc = MFMA16(wa0, xb0, acc);
            acc = MFMA16(wa1, xb1, acc);
            float4 bias = *(const float4*)(bvh + t * 16 + quad * 4);
            const float bs[4] = { bias.x, bias.y, bias.z, bias.w };
            #pragma unroll
            for (int r = 0; r < 4; ++r)
                vlds[(t * 16 + quad * 4 + r) * 72 + wave * 16 + lrow]
                    = f2bf(acc[r] + bs[r]);
        }
    }
    __syncthreads();
    {
        const int er = threadIdx.x >> 2;   // e row 0..63
        const int sc = threadIdx.x & 3;    // chunk of 16 seq
        short8 v0 = *(const short8*)&vlds[er * 72 + sc * 16];
        short8 v1 = *(const short8*)&vlds[er * 72 + sc * 16 + 8];
        unsigned short* dst = Vt + (size_t)bh * 65536 + (size_t)er * 1024
                              + row0 + sc * 16;
        *(short8*)dst = v0;
        *(short8*)(dst + 8) = v1;
    }
}

// ---------------------------------------------------------------------------
// Phase 2 (round-15/18, verbatim): flash attention, M=32/wave, prefetched
// staging, slot-permuted K LDS, register-only P. grid (8, 96), block 256.
// ---------------------------------------------------------------------------
__global__ __launch_bounds__(256) void attn_kernel(
    const unsigned short* __restrict__ Q, const unsigned short* __restrict__ K,
    const unsigned short* __restrict__ Vt, unsigned short* __restrict__ AO)
{
    __shared__ __align__(16) unsigned short Klds[64 * 72];  // 9216 B
    __shared__ __align__(16) unsigned short Vlds[64 * 72];  // 9216 B

    const int bh = (int)blockIdx.x + ((int)blockIdx.y >> 3) * 8;
    const int qb = blockIdx.y & 7;
    const int b = bh / 12, h = bh % 12;
    const int wave = threadIdx.x >> 6, lane = threadIdx.x & 63;
    const int lrow = lane & 15, quad = lane >> 4;
    const int qrow0 = qb * 128 + wave * 32;

    const unsigned short* Qb = Q + (size_t)bh * 65536;
    const unsigned short* Kb = K + (size_t)bh * 65536;
    const unsigned short* Vb = Vt + (size_t)bh * 65536;

    const int tch = threadIdx.x & 7, trow = threadIdx.x >> 3;
    const int slot0 = ((trow & 4) << 2) | ((trow >> 3) << 2) | (trow & 3);

    short8 aq[2][2];
    #pragma unroll
    for (int mm = 0; mm < 2; ++mm) {
        const unsigned short* qr = Qb + (size_t)(qrow0 + mm * 16 + lrow) * 64;
        aq[mm][0] = *(const short8*)(qr + quad * 8);
        aq[mm][1] = *(const short8*)(qr + 32 + quad * 8);
    }

    const floatx4 zero = { 0.f, 0.f, 0.f, 0.f };
    float part[2] = { 0.f, 0.f };
    floatx4 Oacc[2][4];
    #pragma unroll
    for (int mm = 0; mm < 2; ++mm)
        #pragma unroll
        for (int t = 0; t < 4; ++t) Oacc[mm][t] = zero;

    short8 kpre[2], vpre[2];
    kpre[0] = *(const short8*)(Kb + (size_t)trow * 64 + tch * 8);
    kpre[1] = *(const short8*)(Kb + (size_t)(trow + 32) * 64 + tch * 8);
    vpre[0] = *(const short8*)(Vb + (size_t)trow * 1024 + tch * 8);
    vpre[1] = *(const short8*)(Vb + (size_t)(trow + 32) * 1024 + tch * 8);

    for (int jt = 0; jt < 16; ++jt) {
        *(short8*)&Klds[slot0 * 72 + tch * 8] = kpre[0];
        *(short8*)&Klds[(slot0 + 32) * 72 + tch * 8] = kpre[1];
        *(short8*)&Vlds[trow * 72 + tch * 8] = vpre[0];
        *(short8*)&Vlds[(trow + 32) * 72 + tch * 8] = vpre[1];
        __syncthreads();

        {
            const int jn = ((jt + 1) & 15) * 64;
            kpre[0] = *(const short8*)(Kb + (size_t)(jn + trow) * 64 + tch * 8);
            kpre[1] = *(const short8*)(Kb + (size_t)(jn + trow + 32) * 64 + tch * 8);
            vpre[0] = *(const short8*)(Vb + (size_t)trow * 1024 + jn + tch * 8);
            vpre[1] = *(const short8*)(Vb + (size_t)(trow + 32) * 1024 + jn + tch * 8);
        }

        #pragma unroll
        for (int w = 0; w < 2; ++w) {
            short8 kA[2][2];
            #pragma unroll
            for (int tau = 0; tau < 2; ++tau) {
                int kr = w * 32 + tau * 16 + lrow;
                kA[tau][0] = *(const short8*)&Klds[kr * 72 + quad * 8];
                kA[tau][1] = *(const short8*)&Klds[kr * 72 + 32 + quad * 8];
            }
            short8 vA[4];
            #pragma unroll
            for (int t = 0; t < 4; ++t)
                vA[t] = *(const short8*)&Vlds[(t * 16 + lrow) * 72
                                              + w * 32 + quad * 8];

            #pragma unroll
            for (int mm = 0; mm < 2; ++mm) {
                floatx4 s0 = zero, s1 = zero;
                s0 = MFMA16(kA[0][0], aq[mm][0], s0);
                s0 = MFMA16(kA[0][1], aq[mm][1], s0);
                s1 = MFMA16(kA[1][0], aq[mm][0], s1);
                s1 = MFMA16(kA[1][1], aq[mm][1], s1);

                short8 pk;
                #pragma unroll
                for (int r = 0; r < 4; ++r) {
                    float p0 = EXP2(s0[r]);
                    float p1 = EXP2(s1[r]);
                    part[mm] += p0 + p1;
                    pk[r] = (short)f2bf_trunc(p0);
                    pk[4 + r] = (short)f2bf_trunc(p1);
                }
                #pragma unroll
                for (int t = 0; t < 4; ++t)
                    Oacc[mm][t] = MFMA16(vA[t], pk, Oacc[mm][t]);
            }
        }
        __syncthreads();
    }

    #pragma unroll
    for (int mm = 0; mm < 2; ++mm) {
        float ts = part[mm];
        ts += __shfl_xor(ts, 16);
        ts += __shfl_xor(ts, 32);
        float inv = RCP(ts);
        unsigned short* orow = AO
            + ((size_t)(b * 1024 + qrow0 + mm * 16 + lrow)) * 768 + h * 64;
        #pragma unroll
        for (int t = 0; t < 4; ++t) {
            unsigned short pkd[4];
            #pragma unroll
            for (int r = 0; r < 4; ++r)
                pkd[r] = f2bf(Oacc[mm][t][r] * inv);
            *(uint2*)(orow + t * 16 + quad * 4) = *(uint2*)pkd;
        }
    }
}

// ---------------------------------------------------------------------------
// Phase 3: staged GEMM, tile 64x96, BK=64, register-prefetched staging.
// grid (128, 8) = 1024 blocks = 4 blocks/CU = 16 waves/CU.
// block 256 = 2x2 waves of 32r x 48c. Transposed compute D[c][row].
// ---------------------------------------------------------------------------
__global__ __launch_bounds__(256) void out_proj(
    const unsigned short* __restrict__ AO, const unsigned short* __restrict__ Wob,
    const float* __restrict__ bo, float* __restrict__ Y)
{
    __shared__ __align__(16) unsigned short Alds[64 * 72];   //  9216 B
    __shared__ __align__(16) unsigned short Blds[96 * 72];   // 13824 B

    const int wave = threadIdx.x >> 6, lane = threadIdx.x & 63;
    const int lrow = lane & 15, quad = lane >> 4;
    const int row0 = blockIdx.x * 64;
    const int c0 = blockIdx.y * 96;
    const int wrow = (wave >> 1) * 32, wcol = (wave & 1) * 48;

    // staging coords: 8 chunks of 8 u16 per 64-col row; 32 rows per round
    const int tch = threadIdx.x & 7, trow = threadIdx.x >> 3;

    const floatx4 zero = { 0.f, 0.f, 0.f, 0.f };
    floatx4 acc[3][2];  // [c-subtile u][row-subtile t]
    #pragma unroll
    for (int u = 0; u < 3; ++u)
        #pragma unroll
        for (int t = 0; t < 2; ++t) acc[u][t] = zero;

    // prologue: prefetch k-tile 0 (A: rows trow+{0,32}; B: trow+{0,32,64})
    short8 apre[2], bpre[3];
    #pragma unroll
    for (int rr = 0; rr < 2; ++rr)
        apre[rr] = *(const short8*)(AO + (size_t)(row0 + trow + rr * 32) * 768
                                    + tch * 8);
    #pragma unroll
    for (int rr = 0; rr < 3; ++rr)
        bpre[rr] = *(const short8*)(Wob + (size_t)(c0 + trow + rr * 32) * 768
                                    + tch * 8);

    for (int k0 = 0; k0 < 768; k0 += 64) {
        // write staged registers
        #pragma unroll
        for (int rr = 0; rr < 2; ++rr)
            *(short8*)&Alds[(trow + rr * 32) * 72 + tch * 8] = apre[rr];
        #pragma unroll
        for (int rr = 0; rr < 3; ++rr)
            *(short8*)&Blds[(trow + rr * 32) * 72 + tch * 8] = bpre[rr];
        __syncthreads();

        // issue next k-tile's loads (wraps harmlessly on the last iter)
        {
            const int kn = (k0 + 64 < 768) ? k0 + 64 : 0;
            #pragma unroll
            for (int rr = 0; rr < 2; ++rr)
                apre[rr] = *(const short8*)(AO
                    + (size_t)(row0 + trow + rr * 32) * 768 + kn + tch * 8);
            #pragma unroll
            for (int rr = 0; rr < 3; ++rr)
                bpre[rr] = *(const short8*)(Wob
                    + (size_t)(c0 + trow + rr * 32) * 768 + kn + tch * 8);
        }

        // compute: 2 k-chunks of 32, 6 MFMA each
        #pragma unroll
        for (int kc = 0; kc < 2; ++kc) {
            short8 aoF[2], wF[3];
            #pragma unroll
            for (int t = 0; t < 2; ++t)
                aoF[t] = *(const short8*)&Alds[(wrow + t * 16 + lrow) * 72
                                               + kc * 32 + quad * 8];
            #pragma unroll
            for (int u = 0; u < 3; ++u)
                wF[u] = *(const short8*)&Blds[(wcol + u * 16 + lrow) * 72
                                              + kc * 32 + quad * 8];
            #pragma unroll
            for (int u = 0; u < 3; ++u)
                #pragma unroll
                for (int t = 0; t < 2; ++t)
                    acc[u][t] = MFMA16(wF[u], aoF[t], acc[u][t]);  // D[c][row]
        }
        __syncthreads();
    }

    #pragma unroll
    for (int u = 0; u < 3; ++u) {
        const int cb = c0 + wcol + u * 16 + quad * 4;
        float4 bias = *(const float4*)(bo + cb);
        const float bs[4] = { bias.x, bias.y, bias.z, bias.w };
        #pragma unroll
        for (int t = 0; t < 2; ++t) {
            const int row = row0 + wrow + t * 16 + lrow;
            float out[4];
            #pragma unroll
            for (int r = 0; r < 4; ++r) out[r] = acc[u][t][r] + bs[r];
            *(float4*)(Y + (size_t)row * 768 + cb) = *(float4*)out;  // 16B store
        }
    }
}

extern "C" void kernel_launch(void* const* d_in, const int* in_sizes, int n_in,
                              void* d_out, int out_size, void* d_ws, size_t ws_size,
                              hipStream_t stream)
{
    const float* x  = (const float*)d_in[0];
    const float* Wq = (const float*)d_in[1];
    const float* Wk = (const float*)d_in[2];
    const float* Wv = (const float*)d_in[3];
    const float* bq = (const float*)d_in[4];
    const float* bk = (const float*)d_in[5];
    const float* bv = (const float*)d_in[6];
    const float* Wo = (const float*)d_in[7];
    const float* bo = (const float*)d_in[8];

    // ws layout (bf16 elements)
    unsigned short* Q   = (unsigned short*)d_ws;        // 6291456
    unsigned short* K   = Q + 6291456;                  // 6291456
    unsigned short* Vt  = K + 6291456;                  // 6291456 (transposed)
    unsigned short* AO  = Vt + 6291456;                 // 6291456
    unsigned short* Wqt = AO + 6291456;                 // 49152
    unsigned short* Wkt = Wqt + 49152;                  // 49152
    unsigned short* Wvt = Wkt + 49152;                  // 49152
    unsigned short* Wob = Wvt + 49152;                  // 589824
    float* Y = (float*)d_out;

    prep_weights<<<dim3(576), 256, 0, stream>>>(Wq, Wk, Wv, Wo, Wqt, Wkt, Wvt, Wob);
    qkv_proj<<<dim3(16, 96), 256, 0, stream>>>(x, Wqt, Wkt, Wvt, bq, bk, bv, Q, K, Vt);
    attn_kernel<<<dim3(8, 96), 256, 0, stream>>>(Q, K, Vt, AO);
    out_proj<<<dim3(128, 8), 256, 0, stream>>>(AO, Wob, bo, Y);
}

// Round 6
// 166.039 us; speedup vs baseline: 1.0236x; 1.0236x over previous
//
#include <hip/hip_runtime.h>

// MHA: B=8, N=1024, D=768, H=12, HD=64. FLOAT32 in/out, bf16 MFMA internally.
// Round 21: out_proj back to measured-best 128x96 (r20's 64x96 cost ~5us:
//   Wob traffic doubled 75->151MB, reuse-bound not latency-bound) PLUS the
//   one untested variant there: double-buffered LDS, ONE barrier per k-iter.
//   Unlike attn (r19 null at 3 blocks/CU), out_proj has only 2 blocks/CU =
//   8 waves/CU -- least wave cover for the per-barrier vmcnt(0) drain.
// attn: round-15/18 form verbatim (closed: 42-45us across 4 runs).
// qkv/prep unchanged.

typedef __attribute__((ext_vector_type(8))) short short8;   // 8 x bf16 bits
typedef __attribute__((ext_vector_type(4))) float floatx4;  // MFMA acc

#define MFMA16(a, b, c) __builtin_amdgcn_mfma_f32_16x16x32_bf16((a), (b), (c), 0, 0, 0)

#if __has_builtin(__builtin_amdgcn_exp2f)
#define EXP2(x) __builtin_amdgcn_exp2f(x)
#else
#define EXP2(x) __expf(0.6931471805599453f * (x))
#endif
#if __has_builtin(__builtin_amdgcn_rcpf)
#define RCP(x) __builtin_amdgcn_rcpf(x)
#else
#define RCP(x) (1.0f / (x))
#endif

__device__ __forceinline__ unsigned short f2bf(float f) {
    union { float f; unsigned int i; } c;
    c.f = f;
    unsigned int i = c.i;
    return (unsigned short)((i + 0x7fffu + ((i >> 16) & 1u)) >> 16);  // RNE
}
__device__ __forceinline__ unsigned short f2bf_trunc(float f) {
    union { float f; unsigned int i; } c;
    c.f = f;
    return (unsigned short)(c.i >> 16);
}

// ---------------------------------------------------------------------------
// Phase 0: Wt[h][e][k] = W[h][k][e] (bf16), Wo_bf = bf16(Wo).
// ---------------------------------------------------------------------------
__global__ __launch_bounds__(256) void prep_weights(
    const float* __restrict__ Wq, const float* __restrict__ Wk,
    const float* __restrict__ Wv, const float* __restrict__ Wo,
    unsigned short* __restrict__ Wqt, unsigned short* __restrict__ Wkt,
    unsigned short* __restrict__ Wvt, unsigned short* __restrict__ Wob)
{
    int tid = blockIdx.x * 256 + threadIdx.x;  // 0..147455
    if (tid < 49152) {                          // 12 heads * 4096 only
        int h = tid >> 12, r = tid & 4095;
        int e = r >> 6, k = r & 63;
        int src = h * 4096 + k * 64 + e, dst = h * 4096 + e * 64 + k;
        Wqt[dst] = f2bf(Wq[src]);
        Wkt[dst] = f2bf(Wk[src]);
        Wvt[dst] = f2bf(Wv[src]);
    }
    for (int i = tid; i < 589824; i += 147456) Wob[i] = f2bf(Wo[i]);
}

// ---------------------------------------------------------------------------
// Phase 1: staged + transposed QKV. grid (16, 96), block 256.
// ---------------------------------------------------------------------------
__global__ __launch_bounds__(256) void qkv_proj(
    const float* __restrict__ x,
    const unsigned short* __restrict__ Wqt, const unsigned short* __restrict__ Wkt,
    const unsigned short* __restrict__ Wvt,
    const float* __restrict__ bq, const float* __restrict__ bk,
    const float* __restrict__ bv,
    unsigned short* __restrict__ Q, unsigned short* __restrict__ K,
    unsigned short* __restrict__ Vt)
{
    __shared__ __align__(16) unsigned short xlds[64 * 72];  // 9216 B
    __shared__ __align__(16) unsigned short vlds[64 * 72];  // 9216 B

    const int bh = blockIdx.y;
    const int b = bh / 12, h = bh % 12;
    const int wave = threadIdx.x >> 6, lane = threadIdx.x & 63;
    const int lrow = lane & 15, quad = lane >> 4;
    const int row0 = blockIdx.x * 64;
    const float scale = 0.052058776672f;  // 768^-0.5 * log2(e): p = 2^s

    // ---- stage x tile, coalesced: 16 lanes per row, one float4 each ----
    {
        const int tr = threadIdx.x >> 4;        // 16 rows per round
        const int tc = (threadIdx.x & 15) * 4;  // 4 f32 per thread
        #pragma unroll
        for (int rr = 0; rr < 4; ++rr) {
            const int r = tr + rr * 16;
            const float* src = x + ((size_t)(b * 1024 + row0 + r)) * 768
                               + h * 64 + tc;
            float4 f = *(const float4*)src;
            unsigned short pkd[4];
            pkd[0] = f2bf(f.x); pkd[1] = f2bf(f.y);
            pkd[2] = f2bf(f.z); pkd[3] = f2bf(f.w);
            *(uint2*)&xlds[r * 72 + tc] = *(uint2*)pkd;  // 8B LDS write
        }
    }
    __syncthreads();

    short8 xb0 = *(const short8*)&xlds[(wave * 16 + lrow) * 72 + quad * 8];
    short8 xb1 = *(const short8*)&xlds[(wave * 16 + lrow) * 72 + 32 + quad * 8];

    const floatx4 zero = { 0.f, 0.f, 0.f, 0.f };

    const unsigned short* Wm[2] = { Wqt + h * 4096, Wkt + h * 4096 };
    const float* bm[2] = { bq + h * 64, bk + h * 64 };
    unsigned short* Om[2] = {
        Q + ((size_t)bh * 1024 + row0 + wave * 16 + lrow) * 64,
        K + ((size_t)bh * 1024 + row0 + wave * 16 + lrow) * 64 };
    #pragma unroll
    for (int m = 0; m < 2; ++m) {
        const unsigned short* W = Wm[m];
        #pragma unroll
        for (int t = 0; t < 4; ++t) {
            short8 wa0 = *(const short8*)(W + (t * 16 + lrow) * 64 + quad * 8);
            short8 wa1 = *(const short8*)(W + (t * 16 + lrow) * 64 + 32 + quad * 8);
            floatx4 acc = zero;
            acc = MFMA16(wa0, xb0, acc);
            acc = MFMA16(wa1, xb1, acc);
            float4 bias = *(const float4*)(bm[m] + t * 16 + quad * 4);
            const float bs[4] = { bias.x, bias.y, bias.z, bias.w };
            unsigned short pkd[4];
            #pragma unroll
            for (int r = 0; r < 4; ++r) {
                float v = acc[r] + bs[r];
                if (m == 0) v *= scale;
                pkd[r] = f2bf(v);
            }
            *(uint2*)(Om[m] + t * 16 + quad * 4) = *(uint2*)pkd;  // 8B store
        }
    }

    {
        const unsigned short* W = Wvt + h * 4096;
        const float* bvh = bv + h * 64;
        #pragma unroll
        for (int t = 0; t < 4; ++t) {
            short8 wa0 = *(const short8*)(W + (t * 16 + lrow) * 64 + quad * 8);
            short8 wa1 = *(const short8*)(W + (t * 16 + lrow) * 64 + 32 + quad * 8);
            floatx4 acc = zero;
            acc = MFMA16(wa0, xb0, acc);
            acc = MFMA16(wa1, xb1, acc);
            float4 bias = *(const float4*)(bvh + t * 16 + quad * 4);
            const float bs[4] = { bias.x, bias.y, bias.z, bias.w };
            #pragma unroll
            for (int r = 0; r < 4; ++r)
                vlds[(t * 16 + quad * 4 + r) * 72 + wave * 16 + lrow]
                    = f2bf(acc[r] + bs[r]);
        }
    }
    __syncthreads();
    {
        const int er = threadIdx.x >> 2;   // e row 0..63
        const int sc = threadIdx.x & 3;    // chunk of 16 seq
        short8 v0 = *(const short8*)&vlds[er * 72 + sc * 16];
        short8 v1 = *(const short8*)&vlds[er * 72 + sc * 16 + 8];
        unsigned short* dst = Vt + (size_t)bh * 65536 + (size_t)er * 1024
                              + row0 + sc * 16;
        *(short8*)dst = v0;
        *(short8*)(dst + 8) = v1;
    }
}

// ---------------------------------------------------------------------------
// Phase 2 (round-15/18, verbatim): flash attention, M=32/wave, prefetched
// staging, slot-permuted K LDS, register-only P. grid (8, 96), block 256.
// ---------------------------------------------------------------------------
__global__ __launch_bounds__(256) void attn_kernel(
    const unsigned short* __restrict__ Q, const unsigned short* __restrict__ K,
    const unsigned short* __restrict__ Vt, unsigned short* __restrict__ AO)
{
    __shared__ __align__(16) unsigned short Klds[64 * 72];  // 9216 B
    __shared__ __align__(16) unsigned short Vlds[64 * 72];  // 9216 B

    const int bh = (int)blockIdx.x + ((int)blockIdx.y >> 3) * 8;
    const int qb = blockIdx.y & 7;
    const int b = bh / 12, h = bh % 12;
    const int wave = threadIdx.x >> 6, lane = threadIdx.x & 63;
    const int lrow = lane & 15, quad = lane >> 4;
    const int qrow0 = qb * 128 + wave * 32;

    const unsigned short* Qb = Q + (size_t)bh * 65536;
    const unsigned short* Kb = K + (size_t)bh * 65536;
    const unsigned short* Vb = Vt + (size_t)bh * 65536;

    const int tch = threadIdx.x & 7, trow = threadIdx.x >> 3;
    const int slot0 = ((trow & 4) << 2) | ((trow >> 3) << 2) | (trow & 3);

    short8 aq[2][2];
    #pragma unroll
    for (int mm = 0; mm < 2; ++mm) {
        const unsigned short* qr = Qb + (size_t)(qrow0 + mm * 16 + lrow) * 64;
        aq[mm][0] = *(const short8*)(qr + quad * 8);
        aq[mm][1] = *(const short8*)(qr + 32 + quad * 8);
    }

    const floatx4 zero = { 0.f, 0.f, 0.f, 0.f };
    float part[2] = { 0.f, 0.f };
    floatx4 Oacc[2][4];
    #pragma unroll
    for (int mm = 0; mm < 2; ++mm)
        #pragma unroll
        for (int t = 0; t < 4; ++t) Oacc[mm][t] = zero;

    short8 kpre[2], vpre[2];
    kpre[0] = *(const short8*)(Kb + (size_t)trow * 64 + tch * 8);
    kpre[1] = *(const short8*)(Kb + (size_t)(trow + 32) * 64 + tch * 8);
    vpre[0] = *(const short8*)(Vb + (size_t)trow * 1024 + tch * 8);
    vpre[1] = *(const short8*)(Vb + (size_t)(trow + 32) * 1024 + tch * 8);

    for (int jt = 0; jt < 16; ++jt) {
        *(short8*)&Klds[slot0 * 72 + tch * 8] = kpre[0];
        *(short8*)&Klds[(slot0 + 32) * 72 + tch * 8] = kpre[1];
        *(short8*)&Vlds[trow * 72 + tch * 8] = vpre[0];
        *(short8*)&Vlds[(trow + 32) * 72 + tch * 8] = vpre[1];
        __syncthreads();

        {
            const int jn = ((jt + 1) & 15) * 64;
            kpre[0] = *(const short8*)(Kb + (size_t)(jn + trow) * 64 + tch * 8);
            kpre[1] = *(const short8*)(Kb + (size_t)(jn + trow + 32) * 64 + tch * 8);
            vpre[0] = *(const short8*)(Vb + (size_t)trow * 1024 + jn + tch * 8);
            vpre[1] = *(const short8*)(Vb + (size_t)(trow + 32) * 1024 + jn + tch * 8);
        }

        #pragma unroll
        for (int w = 0; w < 2; ++w) {
            short8 kA[2][2];
            #pragma unroll
            for (int tau = 0; tau < 2; ++tau) {
                int kr = w * 32 + tau * 16 + lrow;
                kA[tau][0] = *(const short8*)&Klds[kr * 72 + quad * 8];
                kA[tau][1] = *(const short8*)&Klds[kr * 72 + 32 + quad * 8];
            }
            short8 vA[4];
            #pragma unroll
            for (int t = 0; t < 4; ++t)
                vA[t] = *(const short8*)&Vlds[(t * 16 + lrow) * 72
                                              + w * 32 + quad * 8];

            #pragma unroll
            for (int mm = 0; mm < 2; ++mm) {
                floatx4 s0 = zero, s1 = zero;
                s0 = MFMA16(kA[0][0], aq[mm][0], s0);
                s0 = MFMA16(kA[0][1], aq[mm][1], s0);
                s1 = MFMA16(kA[1][0], aq[mm][0], s1);
                s1 = MFMA16(kA[1][1], aq[mm][1], s1);

                short8 pk;
                #pragma unroll
                for (int r = 0; r < 4; ++r) {
                    float p0 = EXP2(s0[r]);
                    float p1 = EXP2(s1[r]);
                    part[mm] += p0 + p1;
                    pk[r] = (short)f2bf_trunc(p0);
                    pk[4 + r] = (short)f2bf_trunc(p1);
                }
                #pragma unroll
                for (int t = 0; t < 4; ++t)
                    Oacc[mm][t] = MFMA16(vA[t], pk, Oacc[mm][t]);
            }
        }
        __syncthreads();
    }

    #pragma unroll
    for (int mm = 0; mm < 2; ++mm) {
        float ts = part[mm];
        ts += __shfl_xor(ts, 16);
        ts += __shfl_xor(ts, 32);
        float inv = RCP(ts);
        unsigned short* orow = AO
            + ((size_t)(b * 1024 + qrow0 + mm * 16 + lrow)) * 768 + h * 64;
        #pragma unroll
        for (int t = 0; t < 4; ++t) {
            unsigned short pkd[4];
            #pragma unroll
            for (int r = 0; r < 4; ++r)
                pkd[r] = f2bf(Oacc[mm][t][r] * inv);
            *(uint2*)(orow + t * 16 + quad * 4) = *(uint2*)pkd;
        }
    }
}

// ---------------------------------------------------------------------------
// Phase 3: staged GEMM, tile 128x96, BK=64, register-prefetched staging,
// DOUBLE-BUFFERED LDS: one barrier per k-iter (12 barriers vs 24).
// grid (64, 8) = 512 blocks = exactly 2/CU. block 256 = 2x2 waves of 64r x 48c.
// Transposed compute D[c][row] -> float4 Y stores.
// ---------------------------------------------------------------------------
__global__ __launch_bounds__(256) void out_proj(
    const unsigned short* __restrict__ AO, const unsigned short* __restrict__ Wob,
    const float* __restrict__ bo, float* __restrict__ Y)
{
    __shared__ __align__(16) unsigned short Alds[2][128 * 72];  // 36864 B
    __shared__ __align__(16) unsigned short Blds[2][96 * 72];   // 27648 B

    const int wave = threadIdx.x >> 6, lane = threadIdx.x & 63;
    const int lrow = lane & 15, quad = lane >> 4;
    const int row0 = blockIdx.x * 128;
    const int c0 = blockIdx.y * 96;
    const int wrow = (wave >> 1) * 64, wcol = (wave & 1) * 48;

    // staging coords: 8 chunks of 8 u16 per 64-col row; 32 rows per round
    const int tch = threadIdx.x & 7, trow = threadIdx.x >> 3;

    const floatx4 zero = { 0.f, 0.f, 0.f, 0.f };
    floatx4 acc[3][4];  // [c-subtile u][row-subtile t]
    #pragma unroll
    for (int u = 0; u < 3; ++u)
        #pragma unroll
        for (int t = 0; t < 4; ++t) acc[u][t] = zero;

    // prologue: tile0 -> regs -> buf0; tile1 -> regs
    short8 apre[4], bpre[3];
    #pragma unroll
    for (int rr = 0; rr < 4; ++rr)
        apre[rr] = *(const short8*)(AO + (size_t)(row0 + trow + rr * 32) * 768
                                    + tch * 8);
    #pragma unroll
    for (int rr = 0; rr < 3; ++rr)
        bpre[rr] = *(const short8*)(Wob + (size_t)(c0 + trow + rr * 32) * 768
                                    + tch * 8);
    #pragma unroll
    for (int rr = 0; rr < 4; ++rr)
        *(short8*)&Alds[0][(trow + rr * 32) * 72 + tch * 8] = apre[rr];
    #pragma unroll
    for (int rr = 0; rr < 3; ++rr)
        *(short8*)&Blds[0][(trow + rr * 32) * 72 + tch * 8] = bpre[rr];
    #pragma unroll
    for (int rr = 0; rr < 4; ++rr)
        apre[rr] = *(const short8*)(AO + (size_t)(row0 + trow + rr * 32) * 768
                                    + 64 + tch * 8);
    #pragma unroll
    for (int rr = 0; rr < 3; ++rr)
        bpre[rr] = *(const short8*)(Wob + (size_t)(c0 + trow + rr * 32) * 768
                                    + 64 + tch * 8);

    for (int jt = 0; jt < 12; ++jt) {
        __syncthreads();  // buf[jt&1] fully staged; buf[(jt+1)&1] idle

        // write prefetched tile jt+1 into the idle buffer
        {
            const int nb = (jt + 1) & 1;
            #pragma unroll
            for (int rr = 0; rr < 4; ++rr)
                *(short8*)&Alds[nb][(trow + rr * 32) * 72 + tch * 8] = apre[rr];
            #pragma unroll
            for (int rr = 0; rr < 3; ++rr)
                *(short8*)&Blds[nb][(trow + rr * 32) * 72 + tch * 8] = bpre[rr];
        }
        // issue tile jt+2's loads (wraps harmlessly on the last iters)
        {
            const int kn = (jt + 2 < 12) ? (jt + 2) * 64 : 0;
            #pragma unroll
            for (int rr = 0; rr < 4; ++rr)
                apre[rr] = *(const short8*)(AO
                    + (size_t)(row0 + trow + rr * 32) * 768 + kn + tch * 8);
            #pragma unroll
            for (int rr = 0; rr < 3; ++rr)
                bpre[rr] = *(const short8*)(Wob
                    + (size_t)(c0 + trow + rr * 32) * 768 + kn + tch * 8);
        }

        // compute from buf[jt&1]: 2 k-chunks of 32, 12 MFMA each
        const unsigned short* ab = (const unsigned short*)Alds[jt & 1];
        const unsigned short* bb = (const unsigned short*)Blds[jt & 1];
        #pragma unroll
        for (int kc = 0; kc < 2; ++kc) {
            short8 aoF[4], wF[3];
            #pragma unroll
            for (int t = 0; t < 4; ++t)
                aoF[t] = *(const short8*)&ab[(wrow + t * 16 + lrow) * 72
                                             + kc * 32 + quad * 8];
            #pragma unroll
            for (int u = 0; u < 3; ++u)
                wF[u] = *(const short8*)&bb[(wcol + u * 16 + lrow) * 72
                                            + kc * 32 + quad * 8];
            #pragma unroll
            for (int u = 0; u < 3; ++u)
                #pragma unroll
                for (int t = 0; t < 4; ++t)
                    acc[u][t] = MFMA16(wF[u], aoF[t], acc[u][t]);  // D[c][row]
        }
    }

    #pragma unroll
    for (int u = 0; u < 3; ++u) {
        const int cb = c0 + wcol + u * 16 + quad * 4;
        float4 bias = *(const float4*)(bo + cb);
        const float bs[4] = { bias.x, bias.y, bias.z, bias.w };
        #pragma unroll
        for (int t = 0; t < 4; ++t) {
            const int row = row0 + wrow + t * 16 + lrow;
            float out[4];
            #pragma unroll
            for (int r = 0; r < 4; ++r) out[r] = acc[u][t][r] + bs[r];
            *(float4*)(Y + (size_t)row * 768 + cb) = *(float4*)out;  // 16B store
        }
    }
}

extern "C" void kernel_launch(void* const* d_in, const int* in_sizes, int n_in,
                              void* d_out, int out_size, void* d_ws, size_t ws_size,
                              hipStream_t stream)
{
    const float* x  = (const float*)d_in[0];
    const float* Wq = (const float*)d_in[1];
    const float* Wk = (const float*)d_in[2];
    const float* Wv = (const float*)d_in[3];
    const float* bq = (const float*)d_in[4];
    const float* bk = (const float*)d_in[5];
    const float* bv = (const float*)d_in[6];
    const float* Wo = (const float*)d_in[7];
    const float* bo = (const float*)d_in[8];

    // ws layout (bf16 elements)
    unsigned short* Q   = (unsigned short*)d_ws;        // 6291456
    unsigned short* K   = Q + 6291456;                  // 6291456
    unsigned short* Vt  = K + 6291456;                  // 6291456 (transposed)
    unsigned short* AO  = Vt + 6291456;                 // 6291456
    unsigned short* Wqt = AO + 6291456;                 // 49152
    unsigned short* Wkt = Wqt + 49152;                  // 49152
    unsigned short* Wvt = Wkt + 49152;                  // 49152
    unsigned short* Wob = Wvt + 49152;                  // 589824
    float* Y = (float*)d_out;

    prep_weights<<<dim3(576), 256, 0, stream>>>(Wq, Wk, Wv, Wo, Wqt, Wkt, Wvt, Wob);
    qkv_proj<<<dim3(16, 96), 256, 0, stream>>>(x, Wqt, Wkt, Wvt, bq, bk, bv, Q, K, Vt);
    attn_kernel<<<dim3(8, 96), 256, 0, stream>>>(Q, K, Vt, AO);
    out_proj<<<dim3(64, 8), 256, 0, stream>>>(AO, Wob, bo, Y);
}

// Round 7
// 157.585 us; speedup vs baseline: 1.0785x; 1.0536x over previous
//
#include <hip/hip_runtime.h>

// MHA: B=8, N=1024, D=768, H=12, HD=64. FLOAT32 in/out, bf16 MFMA internally.
// Round 22: prep_weights dispatch eliminated (3us kernel + launch gap).
//   qkv: W transpose done in-block via LDS aliased over xlds (dead after
//     xb regs loaded; 2 extra barriers sequence reuse). Wob f32->bf16 is a
//     grid-stride side job here (stream order covers out_proj). Values
//     bit-identical to the prep path (same f2bf).
//   attn: round-15/18 form verbatim (closed: 42-45us, 4 experiments <=0).
//   out_proj: r21 128x96 double-buffered, 1 barrier/k-iter (best measured).

typedef __attribute__((ext_vector_type(8))) short short8;   // 8 x bf16 bits
typedef __attribute__((ext_vector_type(4))) float floatx4;  // MFMA acc

#define MFMA16(a, b, c) __builtin_amdgcn_mfma_f32_16x16x32_bf16((a), (b), (c), 0, 0, 0)

#if __has_builtin(__builtin_amdgcn_exp2f)
#define EXP2(x) __builtin_amdgcn_exp2f(x)
#else
#define EXP2(x) __expf(0.6931471805599453f * (x))
#endif
#if __has_builtin(__builtin_amdgcn_rcpf)
#define RCP(x) __builtin_amdgcn_rcpf(x)
#else
#define RCP(x) (1.0f / (x))
#endif

__device__ __forceinline__ unsigned short f2bf(float f) {
    union { float f; unsigned int i; } c;
    c.f = f;
    unsigned int i = c.i;
    return (unsigned short)((i + 0x7fffu + ((i >> 16) & 1u)) >> 16);  // RNE
}
__device__ __forceinline__ unsigned short f2bf_trunc(float f) {
    union { float f; unsigned int i; } c;
    c.f = f;
    return (unsigned short)(c.i >> 16);
}

// ---------------------------------------------------------------------------
// Phase 1: staged + transposed QKV, in-block W transpose, Wob side-convert.
// grid (16, 96), block 256.
// ---------------------------------------------------------------------------
__global__ __launch_bounds__(256) void qkv_proj(
    const float* __restrict__ x,
    const float* __restrict__ Wq, const float* __restrict__ Wk,
    const float* __restrict__ Wv,
    const float* __restrict__ bq, const float* __restrict__ bk,
    const float* __restrict__ bv,
    const float* __restrict__ Wo, unsigned short* __restrict__ Wob,
    unsigned short* __restrict__ Q, unsigned short* __restrict__ K,
    unsigned short* __restrict__ Vt)
{
    // smem: [0, 13824) = wlds (3 matrices x 64x72 bf16), aliased by xlds
    //       (4608 elems) during x staging; [13824, 18432) = vlds.
    __shared__ __align__(16) unsigned short smem[4 * 4608];  // 36864 B
    unsigned short* const wlds = smem;          // live after barrier 3
    unsigned short* const xlds = smem;          // live: stage -> barrier 2
    unsigned short* const vlds = smem + 3 * 4608;

    const int bh = blockIdx.y;
    const int b = bh / 12, h = bh % 12;
    const int wave = threadIdx.x >> 6, lane = threadIdx.x & 63;
    const int lrow = lane & 15, quad = lane >> 4;
    const int row0 = blockIdx.x * 64;
    const float scale = 0.052058776672f;  // 768^-0.5 * log2(e): p = 2^s

    // ---- side job: Wob = bf16(Wo), grid-stride (589824 elems) ----
    {
        const int gtid = (blockIdx.y * 16 + blockIdx.x) * 256 + threadIdx.x;
        for (int i = gtid; i < 589824; i += 393216) Wob[i] = f2bf(Wo[i]);
    }

    // ---- stage x tile, coalesced: 16 lanes per row, one float4 each ----
    {
        const int tr = threadIdx.x >> 4;        // 16 rows per round
        const int tc = (threadIdx.x & 15) * 4;  // 4 f32 per thread
        #pragma unroll
        for (int rr = 0; rr < 4; ++rr) {
            const int r = tr + rr * 16;
            const float* src = x + ((size_t)(b * 1024 + row0 + r)) * 768
                               + h * 64 + tc;
            float4 f = *(const float4*)src;
            unsigned short pkd[4];
            pkd[0] = f2bf(f.x); pkd[1] = f2bf(f.y);
            pkd[2] = f2bf(f.z); pkd[3] = f2bf(f.w);
            *(uint2*)&xlds[r * 72 + tc] = *(uint2*)pkd;  // 8B LDS write
        }
    }
    __syncthreads();  // (1) x staged

    short8 xb0 = *(const short8*)&xlds[(wave * 16 + lrow) * 72 + quad * 8];
    short8 xb1 = *(const short8*)&xlds[(wave * 16 + lrow) * 72 + 32 + quad * 8];
    __syncthreads();  // (2) all xlds reads done; region reusable as wlds

    // ---- in-block W transpose: Wt[e][k] = bf16(W[k][e]), stride 72 ----
    {
        const float* Wsrc[3] = { Wq + h * 4096, Wk + h * 4096, Wv + h * 4096 };
        #pragma unroll
        for (int m = 0; m < 3; ++m) {
            unsigned short* wd = wlds + m * 4608;
            #pragma unroll
            for (int i = 0; i < 4; ++i) {
                const int f = i * 256 + threadIdx.x;   // float4 index 0..1023
                float4 v = *(const float4*)(Wsrc[m] + f * 4);
                const int k = f >> 4, e0 = (f & 15) << 2;
                wd[(e0 + 0) * 72 + k] = f2bf(v.x);
                wd[(e0 + 1) * 72 + k] = f2bf(v.y);
                wd[(e0 + 2) * 72 + k] = f2bf(v.z);
                wd[(e0 + 3) * 72 + k] = f2bf(v.w);
            }
        }
    }
    __syncthreads();  // (3) weights staged

    const floatx4 zero = { 0.f, 0.f, 0.f, 0.f };

    const float* bm[2] = { bq + h * 64, bk + h * 64 };
    unsigned short* Om[2] = {
        Q + ((size_t)bh * 1024 + row0 + wave * 16 + lrow) * 64,
        K + ((size_t)bh * 1024 + row0 + wave * 16 + lrow) * 64 };
    #pragma unroll
    for (int m = 0; m < 2; ++m) {
        const unsigned short* W = wlds + m * 4608;
        #pragma unroll
        for (int t = 0; t < 4; ++t) {
            short8 wa0 = *(const short8*)(W + (t * 16 + lrow) * 72 + quad * 8);
            short8 wa1 = *(const short8*)(W + (t * 16 + lrow) * 72 + 32 + quad * 8);
            floatx4 acc = zero;
            acc = MFMA16(wa0, xb0, acc);
            acc = MFMA16(wa1, xb1, acc);
            float4 bias = *(const float4*)(bm[m] + t * 16 + quad * 4);
            const float bs[4] = { bias.x, bias.y, bias.z, bias.w };
            unsigned short pkd[4];
            #pragma unroll
            for (int r = 0; r < 4; ++r) {
                float v = acc[r] + bs[r];
                if (m == 0) v *= scale;
                pkd[r] = f2bf(v);
            }
            *(uint2*)(Om[m] + t * 16 + quad * 4) = *(uint2*)pkd;  // 8B store
        }
    }

    {
        const unsigned short* W = wlds + 2 * 4608;
        const float* bvh = bv + h * 64;
        #pragma unroll
        for (int t = 0; t < 4; ++t) {
            short8 wa0 = *(const short8*)(W + (t * 16 + lrow) * 72 + quad * 8);
            short8 wa1 = *(const short8*)(W + (t * 16 + lrow) * 72 + 32 + quad * 8);
            floatx4 acc = zero;
            acc = MFMA16(wa0, xb0, acc);
            acc = MFMA16(wa1, xb1, acc);
            float4 bias = *(const float4*)(bvh + t * 16 + quad * 4);
            const float bs[4] = { bias.x, bias.y, bias.z, bias.w };
            #pragma unroll
            for (int r = 0; r < 4; ++r)
                vlds[(t * 16 + quad * 4 + r) * 72 + wave * 16 + lrow]
                    = f2bf(acc[r] + bs[r]);
        }
    }
    __syncthreads();  // (4) V tile staged
    {
        const int er = threadIdx.x >> 2;   // e row 0..63
        const int sc = threadIdx.x & 3;    // chunk of 16 seq
        short8 v0 = *(const short8*)&vlds[er * 72 + sc * 16];
        short8 v1 = *(const short8*)&vlds[er * 72 + sc * 16 + 8];
        unsigned short* dst = Vt + (size_t)bh * 65536 + (size_t)er * 1024
                              + row0 + sc * 16;
        *(short8*)dst = v0;
        *(short8*)(dst + 8) = v1;
    }
}

// ---------------------------------------------------------------------------
// Phase 2 (round-15/18, verbatim): flash attention, M=32/wave, prefetched
// staging, slot-permuted K LDS, register-only P. grid (8, 96), block 256.
// ---------------------------------------------------------------------------
__global__ __launch_bounds__(256) void attn_kernel(
    const unsigned short* __restrict__ Q, const unsigned short* __restrict__ K,
    const unsigned short* __restrict__ Vt, unsigned short* __restrict__ AO)
{
    __shared__ __align__(16) unsigned short Klds[64 * 72];  // 9216 B
    __shared__ __align__(16) unsigned short Vlds[64 * 72];  // 9216 B

    const int bh = (int)blockIdx.x + ((int)blockIdx.y >> 3) * 8;
    const int qb = blockIdx.y & 7;
    const int b = bh / 12, h = bh % 12;
    const int wave = threadIdx.x >> 6, lane = threadIdx.x & 63;
    const int lrow = lane & 15, quad = lane >> 4;
    const int qrow0 = qb * 128 + wave * 32;

    const unsigned short* Qb = Q + (size_t)bh * 65536;
    const unsigned short* Kb = K + (size_t)bh * 65536;
    const unsigned short* Vb = Vt + (size_t)bh * 65536;

    const int tch = threadIdx.x & 7, trow = threadIdx.x >> 3;
    const int slot0 = ((trow & 4) << 2) | ((trow >> 3) << 2) | (trow & 3);

    short8 aq[2][2];
    #pragma unroll
    for (int mm = 0; mm < 2; ++mm) {
        const unsigned short* qr = Qb + (size_t)(qrow0 + mm * 16 + lrow) * 64;
        aq[mm][0] = *(const short8*)(qr + quad * 8);
        aq[mm][1] = *(const short8*)(qr + 32 + quad * 8);
    }

    const floatx4 zero = { 0.f, 0.f, 0.f, 0.f };
    float part[2] = { 0.f, 0.f };
    floatx4 Oacc[2][4];
    #pragma unroll
    for (int mm = 0; mm < 2; ++mm)
        #pragma unroll
        for (int t = 0; t < 4; ++t) Oacc[mm][t] = zero;

    short8 kpre[2], vpre[2];
    kpre[0] = *(const short8*)(Kb + (size_t)trow * 64 + tch * 8);
    kpre[1] = *(const short8*)(Kb + (size_t)(trow + 32) * 64 + tch * 8);
    vpre[0] = *(const short8*)(Vb + (size_t)trow * 1024 + tch * 8);
    vpre[1] = *(const short8*)(Vb + (size_t)(trow + 32) * 1024 + tch * 8);

    for (int jt = 0; jt < 16; ++jt) {
        *(short8*)&Klds[slot0 * 72 + tch * 8] = kpre[0];
        *(short8*)&Klds[(slot0 + 32) * 72 + tch * 8] = kpre[1];
        *(short8*)&Vlds[trow * 72 + tch * 8] = vpre[0];
        *(short8*)&Vlds[(trow + 32) * 72 + tch * 8] = vpre[1];
        __syncthreads();

        {
            const int jn = ((jt + 1) & 15) * 64;
            kpre[0] = *(const short8*)(Kb + (size_t)(jn + trow) * 64 + tch * 8);
            kpre[1] = *(const short8*)(Kb + (size_t)(jn + trow + 32) * 64 + tch * 8);
            vpre[0] = *(const short8*)(Vb + (size_t)trow * 1024 + jn + tch * 8);
            vpre[1] = *(const short8*)(Vb + (size_t)(trow + 32) * 1024 + jn + tch * 8);
        }

        #pragma unroll
        for (int w = 0; w < 2; ++w) {
            short8 kA[2][2];
            #pragma unroll
            for (int tau = 0; tau < 2; ++tau) {
                int kr = w * 32 + tau * 16 + lrow;
                kA[tau][0] = *(const short8*)&Klds[kr * 72 + quad * 8];
                kA[tau][1] = *(const short8*)&Klds[kr * 72 + 32 + quad * 8];
            }
            short8 vA[4];
            #pragma unroll
            for (int t = 0; t < 4; ++t)
                vA[t] = *(const short8*)&Vlds[(t * 16 + lrow) * 72
                                              + w * 32 + quad * 8];

            #pragma unroll
            for (int mm = 0; mm < 2; ++mm) {
                floatx4 s0 = zero, s1 = zero;
                s0 = MFMA16(kA[0][0], aq[mm][0], s0);
                s0 = MFMA16(kA[0][1], aq[mm][1], s0);
                s1 = MFMA16(kA[1][0], aq[mm][0], s1);
                s1 = MFMA16(kA[1][1], aq[mm][1], s1);

                short8 pk;
                #pragma unroll
                for (int r = 0; r < 4; ++r) {
                    float p0 = EXP2(s0[r]);
                    float p1 = EXP2(s1[r]);
                    part[mm] += p0 + p1;
                    pk[r] = (short)f2bf_trunc(p0);
                    pk[4 + r] = (short)f2bf_trunc(p1);
                }
                #pragma unroll
                for (int t = 0; t < 4; ++t)
                    Oacc[mm][t] = MFMA16(vA[t], pk, Oacc[mm][t]);
            }
        }
        __syncthreads();
    }

    #pragma unroll
    for (int mm = 0; mm < 2; ++mm) {
        float ts = part[mm];
        ts += __shfl_xor(ts, 16);
        ts += __shfl_xor(ts, 32);
        float inv = RCP(ts);
        unsigned short* orow = AO
            + ((size_t)(b * 1024 + qrow0 + mm * 16 + lrow)) * 768 + h * 64;
        #pragma unroll
        for (int t = 0; t < 4; ++t) {
            unsigned short pkd[4];
            #pragma unroll
            for (int r = 0; r < 4; ++r)
                pkd[r] = f2bf(Oacc[mm][t][r] * inv);
            *(uint2*)(orow + t * 16 + quad * 4) = *(uint2*)pkd;
        }
    }
}

// ---------------------------------------------------------------------------
// Phase 3 (r21, verbatim): staged GEMM, tile 128x96, BK=64, double-buffered
// LDS, one barrier per k-iter. grid (64, 8) = 512 blocks = 2/CU.
// ---------------------------------------------------------------------------
__global__ __launch_bounds__(256) void out_proj(
    const unsigned short* __restrict__ AO, const unsigned short* __restrict__ Wob,
    const float* __restrict__ bo, float* __restrict__ Y)
{
    __shared__ __align__(16) unsigned short Alds[2][128 * 72];  // 36864 B
    __shared__ __align__(16) unsigned short Blds[2][96 * 72];   // 27648 B

    const int wave = threadIdx.x >> 6, lane = threadIdx.x & 63;
    const int lrow = lane & 15, quad = lane >> 4;
    const int row0 = blockIdx.x * 128;
    const int c0 = blockIdx.y * 96;
    const int wrow = (wave >> 1) * 64, wcol = (wave & 1) * 48;

    const int tch = threadIdx.x & 7, trow = threadIdx.x >> 3;

    const floatx4 zero = { 0.f, 0.f, 0.f, 0.f };
    floatx4 acc[3][4];  // [c-subtile u][row-subtile t]
    #pragma unroll
    for (int u = 0; u < 3; ++u)
        #pragma unroll
        for (int t = 0; t < 4; ++t) acc[u][t] = zero;

    // prologue: tile0 -> regs -> buf0; tile1 -> regs
    short8 apre[4], bpre[3];
    #pragma unroll
    for (int rr = 0; rr < 4; ++rr)
        apre[rr] = *(const short8*)(AO + (size_t)(row0 + trow + rr * 32) * 768
                                    + tch * 8);
    #pragma unroll
    for (int rr = 0; rr < 3; ++rr)
        bpre[rr] = *(const short8*)(Wob + (size_t)(c0 + trow + rr * 32) * 768
                                    + tch * 8);
    #pragma unroll
    for (int rr = 0; rr < 4; ++rr)
        *(short8*)&Alds[0][(trow + rr * 32) * 72 + tch * 8] = apre[rr];
    #pragma unroll
    for (int rr = 0; rr < 3; ++rr)
        *(short8*)&Blds[0][(trow + rr * 32) * 72 + tch * 8] = bpre[rr];
    #pragma unroll
    for (int rr = 0; rr < 4; ++rr)
        apre[rr] = *(const short8*)(AO + (size_t)(row0 + trow + rr * 32) * 768
                                    + 64 + tch * 8);
    #pragma unroll
    for (int rr = 0; rr < 3; ++rr)
        bpre[rr] = *(const short8*)(Wob + (size_t)(c0 + trow + rr * 32) * 768
                                    + 64 + tch * 8);

    for (int jt = 0; jt < 12; ++jt) {
        __syncthreads();  // buf[jt&1] fully staged; buf[(jt+1)&1] idle

        {
            const int nb = (jt + 1) & 1;
            #pragma unroll
            for (int rr = 0; rr < 4; ++rr)
                *(short8*)&Alds[nb][(trow + rr * 32) * 72 + tch * 8] = apre[rr];
            #pragma unroll
            for (int rr = 0; rr < 3; ++rr)
                *(short8*)&Blds[nb][(trow + rr * 32) * 72 + tch * 8] = bpre[rr];
        }
        {
            const int kn = (jt + 2 < 12) ? (jt + 2) * 64 : 0;
            #pragma unroll
            for (int rr = 0; rr < 4; ++rr)
                apre[rr] = *(const short8*)(AO
                    + (size_t)(row0 + trow + rr * 32) * 768 + kn + tch * 8);
            #pragma unroll
            for (int rr = 0; rr < 3; ++rr)
                bpre[rr] = *(const short8*)(Wob
                    + (size_t)(c0 + trow + rr * 32) * 768 + kn + tch * 8);
        }

        const unsigned short* ab = (const unsigned short*)Alds[jt & 1];
        const unsigned short* bb = (const unsigned short*)Blds[jt & 1];
        #pragma unroll
        for (int kc = 0; kc < 2; ++kc) {
            short8 aoF[4], wF[3];
            #pragma unroll
            for (int t = 0; t < 4; ++t)
                aoF[t] = *(const short8*)&ab[(wrow + t * 16 + lrow) * 72
                                             + kc * 32 + quad * 8];
            #pragma unroll
            for (int u = 0; u < 3; ++u)
                wF[u] = *(const short8*)&bb[(wcol + u * 16 + lrow) * 72
                                            + kc * 32 + quad * 8];
            #pragma unroll
            for (int u = 0; u < 3; ++u)
                #pragma unroll
                for (int t = 0; t < 4; ++t)
                    acc[u][t] = MFMA16(wF[u], aoF[t], acc[u][t]);  // D[c][row]
        }
    }

    #pragma unroll
    for (int u = 0; u < 3; ++u) {
        const int cb = c0 + wcol + u * 16 + quad * 4;
        float4 bias = *(const float4*)(bo + cb);
        const float bs[4] = { bias.x, bias.y, bias.z, bias.w };
        #pragma unroll
        for (int t = 0; t < 4; ++t) {
            const int row = row0 + wrow + t * 16 + lrow;
            float out[4];
            #pragma unroll
            for (int r = 0; r < 4; ++r) out[r] = acc[u][t][r] + bs[r];
            *(float4*)(Y + (size_t)row * 768 + cb) = *(float4*)out;  // 16B store
        }
    }
}

extern "C" void kernel_launch(void* const* d_in, const int* in_sizes, int n_in,
                              void* d_out, int out_size, void* d_ws, size_t ws_size,
                              hipStream_t stream)
{
    const float* x  = (const float*)d_in[0];
    const float* Wq = (const float*)d_in[1];
    const float* Wk = (const float*)d_in[2];
    const float* Wv = (const float*)d_in[3];
    const float* bq = (const float*)d_in[4];
    const float* bk = (const float*)d_in[5];
    const float* bv = (const float*)d_in[6];
    const float* Wo = (const float*)d_in[7];
    const float* bo = (const float*)d_in[8];

    // ws layout (bf16 elements)
    unsigned short* Q   = (unsigned short*)d_ws;        // 6291456
    unsigned short* K   = Q + 6291456;                  // 6291456
    unsigned short* Vt  = K + 6291456;                  // 6291456 (transposed)
    unsigned short* AO  = Vt + 6291456;                 // 6291456
    unsigned short* Wob = AO + 6291456;                 // 589824
    float* Y = (float*)d_out;

    qkv_proj<<<dim3(16, 96), 256, 0, stream>>>(x, Wq, Wk, Wv, bq, bk, bv,
                                               Wo, Wob, Q, K, Vt);
    attn_kernel<<<dim3(8, 96), 256, 0, stream>>>(Q, K, Vt, AO);
    out_proj<<<dim3(64, 8), 256, 0, stream>>>(AO, Wob, bo, Y);
}

// Round 8
// 157.232 us; speedup vs baseline: 1.0809x; 1.0022x over previous
//
#include <hip/hip_runtime.h>

// MHA: B=8, N=1024, D=768, H=12, HD=64. FLOAT32 in/out, bf16 MFMA internally.
// Round 23: attn P-pack via v_perm_b32 (single surgical VALU cut).
//   pk word = __builtin_amdgcn_perm(p1, p0, 0x07060302) -- selects hi16 of
//   each f32 = bit-identical to f2bf_trunc+pack, 4 instrs vs ~12 per (w,mm).
//   Proper intrinsic (not asm): scheduler stays free (r16 lesson).
//   Everything else verbatim from r22 (157.6us best: qkv w/ in-block W
//   transpose + Wob side-job, attn r15 structure, out_proj r21 dbuf).

typedef __attribute__((ext_vector_type(8))) short short8;   // 8 x bf16 bits
typedef __attribute__((ext_vector_type(4))) float floatx4;  // MFMA acc

#define MFMA16(a, b, c) __builtin_amdgcn_mfma_f32_16x16x32_bf16((a), (b), (c), 0, 0, 0)

#if __has_builtin(__builtin_amdgcn_exp2f)
#define EXP2(x) __builtin_amdgcn_exp2f(x)
#else
#define EXP2(x) __expf(0.6931471805599453f * (x))
#endif
#if __has_builtin(__builtin_amdgcn_rcpf)
#define RCP(x) __builtin_amdgcn_rcpf(x)
#else
#define RCP(x) (1.0f / (x))
#endif

__device__ __forceinline__ unsigned short f2bf(float f) {
    union { float f; unsigned int i; } c;
    c.f = f;
    unsigned int i = c.i;
    return (unsigned short)((i + 0x7fffu + ((i >> 16) & 1u)) >> 16);  // RNE
}
__device__ __forceinline__ unsigned int fbits(float f) {
    union { float f; unsigned int i; } c;
    c.f = f;
    return c.i;
}

// ---------------------------------------------------------------------------
// Phase 1: staged + transposed QKV, in-block W transpose, Wob side-convert.
// grid (16, 96), block 256.
// ---------------------------------------------------------------------------
__global__ __launch_bounds__(256) void qkv_proj(
    const float* __restrict__ x,
    const float* __restrict__ Wq, const float* __restrict__ Wk,
    const float* __restrict__ Wv,
    const float* __restrict__ bq, const float* __restrict__ bk,
    const float* __restrict__ bv,
    const float* __restrict__ Wo, unsigned short* __restrict__ Wob,
    unsigned short* __restrict__ Q, unsigned short* __restrict__ K,
    unsigned short* __restrict__ Vt)
{
    // smem: [0, 13824) = wlds (3 matrices x 64x72 bf16), aliased by xlds
    //       (4608 elems) during x staging; [13824, 18432) = vlds.
    __shared__ __align__(16) unsigned short smem[4 * 4608];  // 36864 B
    unsigned short* const wlds = smem;          // live after barrier 3
    unsigned short* const xlds = smem;          // live: stage -> barrier 2
    unsigned short* const vlds = smem + 3 * 4608;

    const int bh = blockIdx.y;
    const int b = bh / 12, h = bh % 12;
    const int wave = threadIdx.x >> 6, lane = threadIdx.x & 63;
    const int lrow = lane & 15, quad = lane >> 4;
    const int row0 = blockIdx.x * 64;
    const float scale = 0.052058776672f;  // 768^-0.5 * log2(e): p = 2^s

    // ---- side job: Wob = bf16(Wo), grid-stride (589824 elems) ----
    {
        const int gtid = (blockIdx.y * 16 + blockIdx.x) * 256 + threadIdx.x;
        for (int i = gtid; i < 589824; i += 393216) Wob[i] = f2bf(Wo[i]);
    }

    // ---- stage x tile, coalesced: 16 lanes per row, one float4 each ----
    {
        const int tr = threadIdx.x >> 4;        // 16 rows per round
        const int tc = (threadIdx.x & 15) * 4;  // 4 f32 per thread
        #pragma unroll
        for (int rr = 0; rr < 4; ++rr) {
            const int r = tr + rr * 16;
            const float* src = x + ((size_t)(b * 1024 + row0 + r)) * 768
                               + h * 64 + tc;
            float4 f = *(const float4*)src;
            unsigned short pkd[4];
            pkd[0] = f2bf(f.x); pkd[1] = f2bf(f.y);
            pkd[2] = f2bf(f.z); pkd[3] = f2bf(f.w);
            *(uint2*)&xlds[r * 72 + tc] = *(uint2*)pkd;  // 8B LDS write
        }
    }
    __syncthreads();  // (1) x staged

    short8 xb0 = *(const short8*)&xlds[(wave * 16 + lrow) * 72 + quad * 8];
    short8 xb1 = *(const short8*)&xlds[(wave * 16 + lrow) * 72 + 32 + quad * 8];
    __syncthreads();  // (2) all xlds reads done; region reusable as wlds

    // ---- in-block W transpose: Wt[e][k] = bf16(W[k][e]), stride 72 ----
    {
        const float* Wsrc[3] = { Wq + h * 4096, Wk + h * 4096, Wv + h * 4096 };
        #pragma unroll
        for (int m = 0; m < 3; ++m) {
            unsigned short* wd = wlds + m * 4608;
            #pragma unroll
            for (int i = 0; i < 4; ++i) {
                const int f = i * 256 + threadIdx.x;   // float4 index 0..1023
                float4 v = *(const float4*)(Wsrc[m] + f * 4);
                const int k = f >> 4, e0 = (f & 15) << 2;
                wd[(e0 + 0) * 72 + k] = f2bf(v.x);
                wd[(e0 + 1) * 72 + k] = f2bf(v.y);
                wd[(e0 + 2) * 72 + k] = f2bf(v.z);
                wd[(e0 + 3) * 72 + k] = f2bf(v.w);
            }
        }
    }
    __syncthreads();  // (3) weights staged

    const floatx4 zero = { 0.f, 0.f, 0.f, 0.f };

    const float* bm[2] = { bq + h * 64, bk + h * 64 };
    unsigned short* Om[2] = {
        Q + ((size_t)bh * 1024 + row0 + wave * 16 + lrow) * 64,
        K + ((size_t)bh * 1024 + row0 + wave * 16 + lrow) * 64 };
    #pragma unroll
    for (int m = 0; m < 2; ++m) {
        const unsigned short* W = wlds + m * 4608;
        #pragma unroll
        for (int t = 0; t < 4; ++t) {
            short8 wa0 = *(const short8*)(W + (t * 16 + lrow) * 72 + quad * 8);
            short8 wa1 = *(const short8*)(W + (t * 16 + lrow) * 72 + 32 + quad * 8);
            floatx4 acc = zero;
            acc = MFMA16(wa0, xb0, acc);
            acc = MFMA16(wa1, xb1, acc);
            float4 bias = *(const float4*)(bm[m] + t * 16 + quad * 4);
            const float bs[4] = { bias.x, bias.y, bias.z, bias.w };
            unsigned short pkd[4];
            #pragma unroll
            for (int r = 0; r < 4; ++r) {
                float v = acc[r] + bs[r];
                if (m == 0) v *= scale;
                pkd[r] = f2bf(v);
            }
            *(uint2*)(Om[m] + t * 16 + quad * 4) = *(uint2*)pkd;  // 8B store
        }
    }

    {
        const unsigned short* W = wlds + 2 * 4608;
        const float* bvh = bv + h * 64;
        #pragma unroll
        for (int t = 0; t < 4; ++t) {
            short8 wa0 = *(const short8*)(W + (t * 16 + lrow) * 72 + quad * 8);
            short8 wa1 = *(const short8*)(W + (t * 16 + lrow) * 72 + 32 + quad * 8);
            floatx4 acc = zero;
            acc = MFMA16(wa0, xb0, acc);
            acc = MFMA16(wa1, xb1, acc);
            float4 bias = *(const float4*)(bvh + t * 16 + quad * 4);
            const float bs[4] = { bias.x, bias.y, bias.z, bias.w };
            #pragma unroll
            for (int r = 0; r < 4; ++r)
                vlds[(t * 16 + quad * 4 + r) * 72 + wave * 16 + lrow]
                    = f2bf(acc[r] + bs[r]);
        }
    }
    __syncthreads();  // (4) V tile staged
    {
        const int er = threadIdx.x >> 2;   // e row 0..63
        const int sc = threadIdx.x & 3;    // chunk of 16 seq
        short8 v0 = *(const short8*)&vlds[er * 72 + sc * 16];
        short8 v1 = *(const short8*)&vlds[er * 72 + sc * 16 + 8];
        unsigned short* dst = Vt + (size_t)bh * 65536 + (size_t)er * 1024
                              + row0 + sc * 16;
        *(short8*)dst = v0;
        *(short8*)(dst + 8) = v1;
    }
}

// ---------------------------------------------------------------------------
// Phase 2: flash attention, M=32/wave, r15 structure; P-pack via v_perm_b32
// (bit-identical to f2bf_trunc+insert, ~8 fewer VALU per (w,mm)).
// grid (8, 96), block 256.
// ---------------------------------------------------------------------------
__global__ __launch_bounds__(256) void attn_kernel(
    const unsigned short* __restrict__ Q, const unsigned short* __restrict__ K,
    const unsigned short* __restrict__ Vt, unsigned short* __restrict__ AO)
{
    __shared__ __align__(16) unsigned short Klds[64 * 72];  // 9216 B
    __shared__ __align__(16) unsigned short Vlds[64 * 72];  // 9216 B

    const int bh = (int)blockIdx.x + ((int)blockIdx.y >> 3) * 8;
    const int qb = blockIdx.y & 7;
    const int b = bh / 12, h = bh % 12;
    const int wave = threadIdx.x >> 6, lane = threadIdx.x & 63;
    const int lrow = lane & 15, quad = lane >> 4;
    const int qrow0 = qb * 128 + wave * 32;

    const unsigned short* Qb = Q + (size_t)bh * 65536;
    const unsigned short* Kb = K + (size_t)bh * 65536;
    const unsigned short* Vb = Vt + (size_t)bh * 65536;

    const int tch = threadIdx.x & 7, trow = threadIdx.x >> 3;
    const int slot0 = ((trow & 4) << 2) | ((trow >> 3) << 2) | (trow & 3);

    short8 aq[2][2];
    #pragma unroll
    for (int mm = 0; mm < 2; ++mm) {
        const unsigned short* qr = Qb + (size_t)(qrow0 + mm * 16 + lrow) * 64;
        aq[mm][0] = *(const short8*)(qr + quad * 8);
        aq[mm][1] = *(const short8*)(qr + 32 + quad * 8);
    }

    const floatx4 zero = { 0.f, 0.f, 0.f, 0.f };
    float part[2] = { 0.f, 0.f };
    floatx4 Oacc[2][4];
    #pragma unroll
    for (int mm = 0; mm < 2; ++mm)
        #pragma unroll
        for (int t = 0; t < 4; ++t) Oacc[mm][t] = zero;

    short8 kpre[2], vpre[2];
    kpre[0] = *(const short8*)(Kb + (size_t)trow * 64 + tch * 8);
    kpre[1] = *(const short8*)(Kb + (size_t)(trow + 32) * 64 + tch * 8);
    vpre[0] = *(const short8*)(Vb + (size_t)trow * 1024 + tch * 8);
    vpre[1] = *(const short8*)(Vb + (size_t)(trow + 32) * 1024 + tch * 8);

    for (int jt = 0; jt < 16; ++jt) {
        *(short8*)&Klds[slot0 * 72 + tch * 8] = kpre[0];
        *(short8*)&Klds[(slot0 + 32) * 72 + tch * 8] = kpre[1];
        *(short8*)&Vlds[trow * 72 + tch * 8] = vpre[0];
        *(short8*)&Vlds[(trow + 32) * 72 + tch * 8] = vpre[1];
        __syncthreads();

        {
            const int jn = ((jt + 1) & 15) * 64;
            kpre[0] = *(const short8*)(Kb + (size_t)(jn + trow) * 64 + tch * 8);
            kpre[1] = *(const short8*)(Kb + (size_t)(jn + trow + 32) * 64 + tch * 8);
            vpre[0] = *(const short8*)(Vb + (size_t)trow * 1024 + jn + tch * 8);
            vpre[1] = *(const short8*)(Vb + (size_t)(trow + 32) * 1024 + jn + tch * 8);
        }

        #pragma unroll
        for (int w = 0; w < 2; ++w) {
            short8 kA[2][2];
            #pragma unroll
            for (int tau = 0; tau < 2; ++tau) {
                int kr = w * 32 + tau * 16 + lrow;
                kA[tau][0] = *(const short8*)&Klds[kr * 72 + quad * 8];
                kA[tau][1] = *(const short8*)&Klds[kr * 72 + 32 + quad * 8];
            }
            short8 vA[4];
            #pragma unroll
            for (int t = 0; t < 4; ++t)
                vA[t] = *(const short8*)&Vlds[(t * 16 + lrow) * 72
                                              + w * 32 + quad * 8];

            #pragma unroll
            for (int mm = 0; mm < 2; ++mm) {
                floatx4 s0 = zero, s1 = zero;
                s0 = MFMA16(kA[0][0], aq[mm][0], s0);
                s0 = MFMA16(kA[0][1], aq[mm][1], s0);
                s1 = MFMA16(kA[1][0], aq[mm][0], s1);
                s1 = MFMA16(kA[1][1], aq[mm][1], s1);

                float p0[4], p1[4];
                #pragma unroll
                for (int r = 0; r < 4; ++r) {
                    p0[r] = EXP2(s0[r]);
                    p1[r] = EXP2(s1[r]);
                    part[mm] += p0[r] + p1[r];
                }
                // pack P to bf16 (trunc) via v_perm_b32: hi16 of each f32.
                short8 pk;
                unsigned int* pw = (unsigned int*)&pk;
                pw[0] = __builtin_amdgcn_perm(fbits(p0[1]), fbits(p0[0]), 0x07060302u);
                pw[1] = __builtin_amdgcn_perm(fbits(p0[3]), fbits(p0[2]), 0x07060302u);
                pw[2] = __builtin_amdgcn_perm(fbits(p1[1]), fbits(p1[0]), 0x07060302u);
                pw[3] = __builtin_amdgcn_perm(fbits(p1[3]), fbits(p1[2]), 0x07060302u);
                #pragma unroll
                for (int t = 0; t < 4; ++t)
                    Oacc[mm][t] = MFMA16(vA[t], pk, Oacc[mm][t]);
            }
        }
        __syncthreads();
    }

    #pragma unroll
    for (int mm = 0; mm < 2; ++mm) {
        float ts = part[mm];
        ts += __shfl_xor(ts, 16);
        ts += __shfl_xor(ts, 32);
        float inv = RCP(ts);
        unsigned short* orow = AO
            + ((size_t)(b * 1024 + qrow0 + mm * 16 + lrow)) * 768 + h * 64;
        #pragma unroll
        for (int t = 0; t < 4; ++t) {
            unsigned short pkd[4];
            #pragma unroll
            for (int r = 0; r < 4; ++r)
                pkd[r] = f2bf(Oacc[mm][t][r] * inv);
            *(uint2*)(orow + t * 16 + quad * 4) = *(uint2*)pkd;
        }
    }
}

// ---------------------------------------------------------------------------
// Phase 3 (r21, verbatim): staged GEMM, tile 128x96, BK=64, double-buffered
// LDS, one barrier per k-iter. grid (64, 8) = 512 blocks = 2/CU.
// ---------------------------------------------------------------------------
__global__ __launch_bounds__(256) void out_proj(
    const unsigned short* __restrict__ AO, const unsigned short* __restrict__ Wob,
    const float* __restrict__ bo, float* __restrict__ Y)
{
    __shared__ __align__(16) unsigned short Alds[2][128 * 72];  // 36864 B
    __shared__ __align__(16) unsigned short Blds[2][96 * 72];   // 27648 B

    const int wave = threadIdx.x >> 6, lane = threadIdx.x & 63;
    const int lrow = lane & 15, quad = lane >> 4;
    const int row0 = blockIdx.x * 128;
    const int c0 = blockIdx.y * 96;
    const int wrow = (wave >> 1) * 64, wcol = (wave & 1) * 48;

    const int tch = threadIdx.x & 7, trow = threadIdx.x >> 3;

    const floatx4 zero = { 0.f, 0.f, 0.f, 0.f };
    floatx4 acc[3][4];  // [c-subtile u][row-subtile t]
    #pragma unroll
    for (int u = 0; u < 3; ++u)
        #pragma unroll
        for (int t = 0; t < 4; ++t) acc[u][t] = zero;

    // prologue: tile0 -> regs -> buf0; tile1 -> regs
    short8 apre[4], bpre[3];
    #pragma unroll
    for (int rr = 0; rr < 4; ++rr)
        apre[rr] = *(const short8*)(AO + (size_t)(row0 + trow + rr * 32) * 768
                                    + tch * 8);
    #pragma unroll
    for (int rr = 0; rr < 3; ++rr)
        bpre[rr] = *(const short8*)(Wob + (size_t)(c0 + trow + rr * 32) * 768
                                    + tch * 8);
    #pragma unroll
    for (int rr = 0; rr < 4; ++rr)
        *(short8*)&Alds[0][(trow + rr * 32) * 72 + tch * 8] = apre[rr];
    #pragma unroll
    for (int rr = 0; rr < 3; ++rr)
        *(short8*)&Blds[0][(trow + rr * 32) * 72 + tch * 8] = bpre[rr];
    #pragma unroll
    for (int rr = 0; rr < 4; ++rr)
        apre[rr] = *(const short8*)(AO + (size_t)(row0 + trow + rr * 32) * 768
                                    + 64 + tch * 8);
    #pragma unroll
    for (int rr = 0; rr < 3; ++rr)
        bpre[rr] = *(const short8*)(Wob + (size_t)(c0 + trow + rr * 32) * 768
                                    + 64 + tch * 8);

    for (int jt = 0; jt < 12; ++jt) {
        __syncthreads();  // buf[jt&1] fully staged; buf[(jt+1)&1] idle

        {
            const int nb = (jt + 1) & 1;
            #pragma unroll
            for (int rr = 0; rr < 4; ++rr)
                *(short8*)&Alds[nb][(trow + rr * 32) * 72 + tch * 8] = apre[rr];
            #pragma unroll
            for (int rr = 0; rr < 3; ++rr)
                *(short8*)&Blds[nb][(trow + rr * 32) * 72 + tch * 8] = bpre[rr];
        }
        {
            const int kn = (jt + 2 < 12) ? (jt + 2) * 64 : 0;
            #pragma unroll
            for (int rr = 0; rr < 4; ++rr)
                apre[rr] = *(const short8*)(AO
                    + (size_t)(row0 + trow + rr * 32) * 768 + kn + tch * 8);
            #pragma unroll
            for (int rr = 0; rr < 3; ++rr)
                bpre[rr] = *(const short8*)(Wob
                    + (size_t)(c0 + trow + rr * 32) * 768 + kn + tch * 8);
        }

        const unsigned short* ab = (const unsigned short*)Alds[jt & 1];
        const unsigned short* bb = (const unsigned short*)Blds[jt & 1];
        #pragma unroll
        for (int kc = 0; kc < 2; ++kc) {
            short8 aoF[4], wF[3];
            #pragma unroll
            for (int t = 0; t < 4; ++t)
                aoF[t] = *(const short8*)&ab[(wrow + t * 16 + lrow) * 72
                                             + kc * 32 + quad * 8];
            #pragma unroll
            for (int u = 0; u < 3; ++u)
                wF[u] = *(const short8*)&bb[(wcol + u * 16 + lrow) * 72
                                            + kc * 32 + quad * 8];
            #pragma unroll
            for (int u = 0; u < 3; ++u)
                #pragma unroll
                for (int t = 0; t < 4; ++t)
                    acc[u][t] = MFMA16(wF[u], aoF[t], acc[u][t]);  // D[c][row]
        }
    }

    #pragma unroll
    for (int u = 0; u < 3; ++u) {
        const int cb = c0 + wcol + u * 16 + quad * 4;
        float4 bias = *(const float4*)(bo + cb);
        const float bs[4] = { bias.x, bias.y, bias.z, bias.w };
        #pragma unroll
        for (int t = 0; t < 4; ++t) {
            const int row = row0 + wrow + t * 16 + lrow;
            float out[4];
            #pragma unroll
            for (int r = 0; r < 4; ++r) out[r] = acc[u][t][r] + bs[r];
            *(float4*)(Y + (size_t)row * 768 + cb) = *(float4*)out;  // 16B store
        }
    }
}

extern "C" void kernel_launch(void* const* d_in, const int* in_sizes, int n_in,
                              void* d_out, int out_size, void* d_ws, size_t ws_size,
                              hipStream_t stream)
{
    const float* x  = (const float*)d_in[0];
    const float* Wq = (const float*)d_in[1];
    const float* Wk = (const float*)d_in[2];
    const float* Wv = (const float*)d_in[3];
    const float* bq = (const float*)d_in[4];
    const float* bk = (const float*)d_in[5];
    const float* bv = (const float*)d_in[6];
    const float* Wo = (const float*)d_in[7];
    const float* bo = (const float*)d_in[8];

    // ws layout (bf16 elements)
    unsigned short* Q   = (unsigned short*)d_ws;        // 6291456
    unsigned short* K   = Q + 6291456;                  // 6291456
    unsigned short* Vt  = K + 6291456;                  // 6291456 (transposed)
    unsigned short* AO  = Vt + 6291456;                 // 6291456
    unsigned short* Wob = AO + 6291456;                 // 589824
    float* Y = (float*)d_out;

    qkv_proj<<<dim3(16, 96), 256, 0, stream>>>(x, Wq, Wk, Wv, bq, bk, bv,
                                               Wo, Wob, Q, K, Vt);
    attn_kernel<<<dim3(8, 96), 256, 0, stream>>>(Q, K, Vt, AO);
    out_proj<<<dim3(64, 8), 256, 0, stream>>>(AO, Wob, bo, Y);
}